// Round 8
// baseline (171.319 us; speedup 1.0000x reference)
//
#include <hip/hip_runtime.h>
#include <hip/hip_bf16.h>
#include <hip/hip_fp8.h>

typedef __attribute__((ext_vector_type(8))) short bf16x8;
typedef __attribute__((ext_vector_type(4))) float f32x4;
typedef long long i64;
typedef __attribute__((ext_vector_type(2))) long long i64x2;

#define HW 36864
#define HID 340
#define HPAD 352
#define ECP 1408
#define NCHUNK 44
#define TILE 96
#define TILES_PER_B 384
#define OUT_Y_ELEMS 9437184
#define WALL_BYTES (NCHUNK * 8192)

__device__ __forceinline__ short f2bf(float f) {
    __hip_bfloat16 h = __float2bfloat16(f);
    union { __hip_bfloat16 h; short s; } u; u.h = h; return u.s;
}
__device__ __forceinline__ f32x4 mfma_fp8(i64 a, i64 b, f32x4 c) {
    return __builtin_amdgcn_mfma_f32_16x16x32_fp8_fp8(a, b, c, 0, 0, 0);
}

// ---------------- K_prep: emb + fp8 weight prepack (lane-contiguous layout) + b1c ----------------
__global__ __launch_bounds__(256) void k_prep(const float* __restrict__ x,
                                              const float* __restrict__ w1, const float* __restrict__ w2,
                                              const float* __restrict__ b1,
                                              float* __restrict__ emb, unsigned char* __restrict__ Wall,
                                              float* __restrict__ b1c) {
    int blk = blockIdx.x;
    int tid = threadIdx.x;
    if (blk < 256) {
        const float* p = x + (size_t)blk * HW;
        float s = 0.f;
        for (int i = tid * 4; i < HW; i += 1024) {
            float4 v = *(const float4*)(p + i);
            s += v.x + v.y + v.z + v.w;
        }
        for (int off = 32; off; off >>= 1) s += __shfl_down(s, off);
        __shared__ float wsum[4];
        int lane = tid & 63, wid = tid >> 6;
        if (lane == 0) wsum[wid] = s;
        __syncthreads();
        if (tid == 0) emb[blk] = (wsum[0] + wsum[1] + wsum[2] + wsum[3]) * (1.f / (float)HW);
        return;
    }
    if (blk < 608) {
        int idx4 = (blk - 256) * 1024 + tid * 4;   // 4-aligned
        int ch = idx4 >> 13, r = idx4 & 8191;
        float v0 = 0.f, v1 = 0.f, v2 = 0.f, v3 = 0.f;
        if (r < 4096) {
            int jj0 = r & 7;                  // 0 or 4
            int kk = (r >> 3) & 3;
            int lane_id = (r >> 5) & 127;
            int l16 = lane_id & 15;
            int gm = lane_id >> 4;            // g16*2 + m
            int g16 = gm >> 1, m = gm & 1;
            int j = ch * 32 + m * 16 + l16;
            int c0 = 16 * (2 * kk + (jj0 >> 2)) + 4 * g16;
            int e = j / HPAD, h = j - e * HPAD;
            if (h < HID) {
                const float* p = w1 + ((size_t)(e * 128 + c0)) * HID + h;
                v0 = p[0] * 32.f; v1 = p[HID] * 32.f; v2 = p[2 * HID] * 32.f; v3 = p[3 * HID] * 32.f;
            }
        } else {
            int r2 = r - 4096;
            int jj0 = r2 & 7;                 // 0 or 4
            int oc = (r2 >> 3) & 7;
            int lane = (r2 >> 6) & 63;
            int l16 = lane & 15, g16 = lane >> 4;
            int o = oc * 16 + l16;
            int jg0 = ch * 32 + 16 * (jj0 >> 2) + 4 * g16;
            int e = jg0 / HPAD, h = jg0 - e * HPAD;
            if (h < HID) {
                const float* p = w2 + ((size_t)(e * HID + h)) * 128 + o;
                v0 = p[0] * 32.f; v1 = p[128] * 32.f; v2 = p[256] * 32.f; v3 = p[384] * 32.f;
            }
        }
        unsigned w = __builtin_amdgcn_cvt_pk_fp8_f32(v0, v1, 0, false);
        w = __builtin_amdgcn_cvt_pk_fp8_f32(v2, v3, w, true);
        *(unsigned*)(Wall + idx4) = w;
        return;
    }
    {
        int j0 = (blk - 608) * 1024 + tid * 4;
        if (j0 < ECP) {
            int e = j0 / HPAD, h = j0 - e * HPAD;
            float4 o;
            if (h < HID) {
                const float* p = b1 + e * HID + h;
                o.x = p[0]; o.y = p[1]; o.z = p[2]; o.w = p[3];
            } else {
                o.x = o.y = o.z = o.w = 0.f;
            }
            *(float4*)(b1c + j0) = o;
        }
    }
}

// ---------------- K_wb: prompt path (redundant per block) + folded conv weights ----------------
__global__ __launch_bounds__(256) void k_wb(const float* __restrict__ emb, const float* __restrict__ prompt,
                                            const float* __restrict__ wlin, const float* __restrict__ blin,
                                            const float* __restrict__ wconv,
                                            short* __restrict__ WbBf, float* __restrict__ stat) {
    __shared__ float lp[2][5];
    __shared__ float pw[2][5];
    __shared__ float sv[2][128];
    int tid = threadIdx.x;
    if (tid < 10) {
        int b = tid / 5, p = tid % 5;
        float s = blin[p];
        for (int c = 0; c < 128; ++c) s += emb[b * 128 + c] * wlin[p * 128 + c];
        lp[b][p] = s;
    }
    __syncthreads();
    if (tid < 2) {
        float m = lp[tid][0];
        for (int p = 1; p < 5; ++p) m = fmaxf(m, lp[tid][p]);
        float e[5], sum = 0.f;
        for (int p = 0; p < 5; ++p) { e[p] = __expf(lp[tid][p] - m); sum += e[p]; }
        for (int p = 0; p < 5; ++p) pw[tid][p] = e[p] / sum;
    }
    __syncthreads();
    {
        int b = tid >> 7, c = tid & 127;
        float s = 0.f;
        for (int p = 0; p < 5; ++p) s += pw[b][p] * prompt[p * 128 + c];
        sv[b][c] = s;
    }
    __syncthreads();
    int i0 = blockIdx.x * 1024 + tid * 4;
    int b = i0 >> 14, o = (i0 >> 7) & 127, c = i0 & 127;
    float4 wv = *(const float4*)(wconv + o * 128 + c);
    short r0 = f2bf(wv.x * sv[b][c]);
    short r1 = f2bf(wv.y * sv[b][c + 1]);
    short r2 = f2bf(wv.z * sv[b][c + 2]);
    short r3 = f2bf(wv.w * sv[b][c + 3]);
    WbBf[i0] = r0; WbBf[i0 + 1] = r1; WbBf[i0 + 2] = r2; WbBf[i0 + 3] = r3;
    if (blockIdx.x == 0 && tid < 8) stat[tid] = 0.f;
}

// ---- wide fragment loads ----
#define LF1(CH) do { \
    const unsigned char* p_ = wb1 + (size_t)(CH) * 8192; \
    f1q[0][0] = *(const i64x2*)(p_); \
    f1q[0][1] = *(const i64x2*)(p_ + 16); \
    f1q[1][0] = *(const i64x2*)(p_ + 512); \
    f1q[1][1] = *(const i64x2*)(p_ + 528); \
} while (0)
#define LF2TO(CH, BUF) do { \
    const unsigned char* p_ = wb2 + (size_t)(CH) * 8192; \
    (BUF)[0] = *(const i64x2*)(p_); \
    (BUF)[1] = *(const i64x2*)(p_ + 16); \
    (BUF)[2] = *(const i64x2*)(p_ + 32); \
    (BUF)[3] = *(const i64x2*)(p_ + 48); \
} while (0)

// fc1 of chunk: fill HC from f1q (current frags) x tyb8
#define FC1_BODY(HC) do { \
    HC[0][0] = (f32x4){0.f,0.f,0.f,0.f}; HC[0][1] = (f32x4){0.f,0.f,0.f,0.f}; \
    HC[1][0] = (f32x4){0.f,0.f,0.f,0.f}; HC[1][1] = (f32x4){0.f,0.f,0.f,0.f}; \
    _Pragma("unroll") \
    for (int kk = 0; kk < 4; ++kk) { \
        i64 a0 = f1q[0][kk >> 1][kk & 1]; \
        i64 a1 = f1q[1][kk >> 1][kk & 1]; \
        HC[0][0] = mfma_fp8(a0, tyb8[0][kk], HC[0][0]); \
        HC[0][1] = mfma_fp8(a0, tyb8[1][kk], HC[0][1]); \
        HC[1][0] = mfma_fp8(a1, tyb8[0][kk], HC[1][0]); \
        HC[1][1] = mfma_fp8(a1, tyb8[1][kk], HC[1][1]); \
    } \
} while (0)

// finish chunk CHP: gelu+gate from HP -> fp8 frags -> fc2 with F2P into accy
#define FIN_BODY(CHP, HP, F2P) do { \
    int chp_ = (CHP); \
    int e4_ = (chp_ >= 33) ? 3 : (chp_ >= 22) ? 2 : (chp_ >= 11) ? 1 : 0; \
    float ge0_ = (e4_ == 0) ? gt0[0] : (e4_ == 1) ? gt0[1] : (e4_ == 2) ? gt0[2] : gt0[3]; \
    float ge1_ = (e4_ == 0) ? gt1[0] : (e4_ == 1) ? gt1[1] : (e4_ == 2) ? gt1[2] : gt1[3]; \
    f32x4 b1v0 = *(const f32x4*)&b1s[chp_ * 32 + 4 * g16]; \
    f32x4 b1v1 = *(const f32x4*)&b1s[chp_ * 32 + 16 + 4 * g16]; \
    float hv0[8], hv1[8]; \
    _Pragma("unroll") \
    for (int jc = 0; jc < 2; ++jc) \
        _Pragma("unroll") \
        for (int rr = 0; rr < 4; ++rr) { \
            float bv = jc ? b1v1[rr] : b1v0[rr]; \
            float u0 = HP[jc][0][rr] * 4.8828125e-4f + bv; \
            float u1 = HP[jc][1][rr] * 4.8828125e-4f + bv; \
            hv0[jc * 4 + rr] = u0 * (1024.f + 816.9738f * u0) * ge0_; \
            hv1[jc * 4 + rr] = u1 * (1024.f + 816.9738f * u1) * ge1_; \
        } \
    union { i64 l; unsigned u[2]; } f0, f1; \
    { \
        unsigned lo = __builtin_amdgcn_cvt_pk_fp8_f32(hv0[0], hv0[1], 0, false); \
        lo = __builtin_amdgcn_cvt_pk_fp8_f32(hv0[2], hv0[3], lo, true); \
        unsigned hi = __builtin_amdgcn_cvt_pk_fp8_f32(hv0[4], hv0[5], 0, false); \
        hi = __builtin_amdgcn_cvt_pk_fp8_f32(hv0[6], hv0[7], hi, true); \
        f0.u[0] = lo; f0.u[1] = hi; \
        lo = __builtin_amdgcn_cvt_pk_fp8_f32(hv1[0], hv1[1], 0, false); \
        lo = __builtin_amdgcn_cvt_pk_fp8_f32(hv1[2], hv1[3], lo, true); \
        hi = __builtin_amdgcn_cvt_pk_fp8_f32(hv1[4], hv1[5], 0, false); \
        hi = __builtin_amdgcn_cvt_pk_fp8_f32(hv1[6], hv1[7], hi, true); \
        f1.u[0] = lo; f1.u[1] = hi; \
    } \
    _Pragma("unroll") \
    for (int oc = 0; oc < 8; ++oc) { \
        i64 wv = (F2P)[oc >> 1][oc & 1]; \
        accy[0][oc] = mfma_fp8(wv, f0.l, accy[0][oc]); \
        accy[1][oc] = mfma_fp8(wv, f1.l, accy[1][oc]); \
    } \
} while (0)

// ---------------- K_main: 768 blocks x 192 threads (3 waves x 32 tokens) ----------------
__global__ __launch_bounds__(192, 3) void k_main(
    const float* __restrict__ x, const float* __restrict__ wgate, const float* __restrict__ b2,
    const short* __restrict__ WbBf, const unsigned char* __restrict__ Wall,
    const float* __restrict__ b1c, float* __restrict__ stat, float* __restrict__ out) {

    __shared__ __align__(16) short Xs[TILE][136];
    __shared__ float gates[TILE][4];
    __shared__ float wg[128][4];
    __shared__ __align__(16) float b1s[ECP];
    __shared__ __align__(16) float b2s[512];
    __shared__ float simp[4], sload[4];

    int tid = threadIdx.x;
    int tb = blockIdx.x;
    int b = tb / TILES_PER_B;
    int hw0 = (tb % TILES_PER_B) * TILE;
    const float* xb = x + (size_t)b * 128 * HW + hw0;

    for (int i = tid; i < 512; i += 192) ((float*)wg)[i] = wgate[i];
    for (int i = tid; i < 512; i += 192) b2s[i] = b2[i];
    for (int i = tid; i < ECP; i += 192) b1s[i] = b1c[i];
    if (tid < 4) { simp[tid] = 0.f; sload[tid] = 0.f; }

    // ---- stage X tile (bf16) ----
    #pragma unroll
    for (int it = 0; it < 16; ++it) {
        int i = tid + it * 192;
        int c = i / 24;
        int k = i - c * 24;
        float4 v = *(const float4*)(xb + (size_t)c * HW + k * 4);
        int t = k * 4;
        Xs[t][c] = f2bf(v.x); Xs[t + 1][c] = f2bf(v.y);
        Xs[t + 2][c] = f2bf(v.z); Xs[t + 3][c] = f2bf(v.w);
    }
    __syncthreads();

    int lane = tid & 63, wid = tid >> 6;
    int g16 = lane >> 4, l16 = lane & 15;
    int wrow = wid * 32;

    const unsigned char* wb1 = Wall + ((g16 * 32 + l16) * 32);
    const unsigned char* wb2 = Wall + 4096 + ((g16 * 16 + l16) * 64);

    // hoisted fc1 chunk-0 frag load (covered by gating+conv compute)
    i64x2 f1q[2][2];
    i64x2 f2qA[4], f2qB[4];
    LF1(0);

    // ---- X fragments (shared by gating MFMA and conv MFMA) ----
    bf16x8 xf[2][4];
    #pragma unroll
    for (int nt = 0; nt < 2; ++nt)
        #pragma unroll
        for (int kk = 0; kk < 4; ++kk)
            xf[nt][kk] = *(const bf16x8*)&Xs[wrow + nt * 16 + l16][kk * 32 + g16 * 8];

    // ---- gating via MFMA: A = wgate^T padded to 16 rows (rows>=4 zero) ----
    {
        bf16x8 wgA[4];
        #pragma unroll
        for (int kk = 0; kk < 4; ++kk) {
            bf16x8 a = (bf16x8){0, 0, 0, 0, 0, 0, 0, 0};
            if (l16 < 4) {
                #pragma unroll
                for (int jj = 0; jj < 8; ++jj)
                    a[jj] = f2bf(wg[kk * 32 + g16 * 8 + jj][l16]);
            }
            wgA[kk] = a;
        }
        f32x4 lg0 = (f32x4){0.f, 0.f, 0.f, 0.f};
        f32x4 lg1 = (f32x4){0.f, 0.f, 0.f, 0.f};
        #pragma unroll
        for (int kk = 0; kk < 4; ++kk) {
            lg0 = __builtin_amdgcn_mfma_f32_16x16x32_bf16(wgA[kk], xf[0][kk], lg0, 0, 0, 0);
            lg1 = __builtin_amdgcn_mfma_f32_16x16x32_bf16(wgA[kk], xf[1][kk], lg1, 0, 0, 0);
        }
        if (g16 == 0) {
            #pragma unroll
            for (int nt = 0; nt < 2; ++nt) {
                f32x4 lg = nt ? lg1 : lg0;
                float l0 = lg[0], l1 = lg[1], l2 = lg[2], l3 = lg[3];
                int i1 = 0; float m1 = l0;
                if (l1 > m1) { m1 = l1; i1 = 1; }
                if (l2 > m1) { m1 = l2; i1 = 2; }
                if (l3 > m1) { m1 = l3; i1 = 3; }
                float m2 = -3.4e38f; int i2 = 0;
                if (i1 != 0) { m2 = l0; i2 = 0; }
                if (i1 != 1 && l1 > m2) { m2 = l1; i2 = 1; }
                if (i1 != 2 && l2 > m2) { m2 = l2; i2 = 2; }
                if (i1 != 3 && l3 > m2) { m2 = l3; i2 = 3; }
                float g2v = 1.f / (1.f + __expf(m1 - m2));
                float g1v = 1.f - g2v;
                int t = wrow + nt * 16 + l16;
                gates[t][0] = 0.f; gates[t][1] = 0.f; gates[t][2] = 0.f; gates[t][3] = 0.f;
                gates[t][i1] = g1v; gates[t][i2] = g2v;
                atomicAdd(&simp[i1], g1v); atomicAdd(&simp[i2], g2v);
                atomicAdd(&sload[i1], 1.f); atomicAdd(&sload[i2], 1.f);
            }
        }
    }

    // ---- conv (bf16): aty[nt][oc] = ty[t][o] ----
    f32x4 aty[2][8];
    #pragma unroll
    for (int nt = 0; nt < 2; ++nt)
        #pragma unroll
        for (int oc = 0; oc < 8; ++oc) aty[nt][oc] = (f32x4){0.f, 0.f, 0.f, 0.f};
    {
        const short* wbB = WbBf + b * 16384 + l16 * 128 + g16 * 8;
        #pragma unroll
        for (int oc = 0; oc < 8; ++oc) {
            #pragma unroll
            for (int kk = 0; kk < 4; ++kk) {
                bf16x8 wv = *(const bf16x8*)(wbB + oc * 16 * 128 + kk * 32);
                aty[0][oc] = __builtin_amdgcn_mfma_f32_16x16x32_bf16(wv, xf[0][kk], aty[0][oc], 0, 0, 0);
                aty[1][oc] = __builtin_amdgcn_mfma_f32_16x16x32_bf16(wv, xf[1][kk], aty[1][oc], 0, 0, 0);
            }
        }
    }
    // repack to fp8 B-fragments (x64 prescale)
    i64 tyb8[2][4];
    #pragma unroll
    for (int nt = 0; nt < 2; ++nt)
        #pragma unroll
        for (int kk = 0; kk < 4; ++kk) {
            union { i64 l; unsigned u[2]; } uu;
            float v0 = aty[nt][2 * kk][0] * 64.f,     v1 = aty[nt][2 * kk][1] * 64.f;
            float v2 = aty[nt][2 * kk][2] * 64.f,     v3 = aty[nt][2 * kk][3] * 64.f;
            float v4 = aty[nt][2 * kk + 1][0] * 64.f, v5 = aty[nt][2 * kk + 1][1] * 64.f;
            float v6 = aty[nt][2 * kk + 1][2] * 64.f, v7 = aty[nt][2 * kk + 1][3] * 64.f;
            unsigned lo = __builtin_amdgcn_cvt_pk_fp8_f32(v0, v1, 0, false);
            lo = __builtin_amdgcn_cvt_pk_fp8_f32(v2, v3, lo, true);
            unsigned hi = __builtin_amdgcn_cvt_pk_fp8_f32(v4, v5, 0, false);
            hi = __builtin_amdgcn_cvt_pk_fp8_f32(v6, v7, hi, true);
            uu.u[0] = lo; uu.u[1] = hi;
            tyb8[nt][kk] = uu.l;
        }

    // per-lane gates (same-wave LDS write->read)
    f32x4 gt0 = *(const f32x4*)&gates[wrow + l16][0];
    f32x4 gt1 = *(const f32x4*)&gates[wrow + 16 + l16][0];

    f32x4 accy[2][8];
    #pragma unroll
    for (int nt = 0; nt < 2; ++nt)
        #pragma unroll
        for (int oc = 0; oc < 8; ++oc) accy[nt][oc] = (f32x4){0.f, 0.f, 0.f, 0.f};

    // ---- cross-chunk pipelined loop: fc1(ch) overlaps gelu+fc2(ch-1) ----
    f32x4 haccA[2][2], haccB[2][2];

    // body 0 (peeled)
    LF2TO(0, f2qA);
    FC1_BODY(haccA);
    LF1(1);

    #pragma unroll 1
    for (int pp = 0; pp < 21; ++pp) {
        int ch1 = 2 * pp + 1;
        LF2TO(ch1, f2qB);
        FC1_BODY(haccB);
        LF1(ch1 + 1);
        FIN_BODY(ch1 - 1, haccA, f2qA);
        int ch2 = 2 * pp + 2;
        LF2TO(ch2, f2qA);
        FC1_BODY(haccA);
        LF1(ch2 + 1);
        FIN_BODY(ch2 - 1, haccB, f2qB);
    }
    // body 43 (peeled, no LF1 beyond)
    LF2TO(43, f2qB);
    FC1_BODY(haccB);
    FIN_BODY(42, haccA, f2qA);
    // final finish
    FIN_BODY(43, haccB, f2qB);

    // ---- epilogue: descale + gates.b2 + residual, store ----
    #pragma unroll
    for (int oc = 0; oc < 8; ++oc) {
        f32x4 b2v0 = *(const f32x4*)&b2s[0 * 128 + oc * 16 + 4 * g16];
        f32x4 b2v1 = *(const f32x4*)&b2s[1 * 128 + oc * 16 + 4 * g16];
        f32x4 b2v2 = *(const f32x4*)&b2s[2 * 128 + oc * 16 + 4 * g16];
        f32x4 b2v3 = *(const f32x4*)&b2s[3 * 128 + oc * 16 + 4 * g16];
        #pragma unroll
        for (int nt = 0; nt < 2; ++nt) {
            f32x4 gt = nt ? gt1 : gt0;
            #pragma unroll
            for (int r = 0; r < 4; ++r) {
                int o = oc * 16 + 4 * g16 + r;
                size_t addr = (size_t)(b * 128 + o) * HW + hw0 + wrow + nt * 16 + l16;
                float v = accy[nt][oc][r] * 1.52587890625e-5f
                        + gt[0] * b2v0[r] + gt[1] * b2v1[r] + gt[2] * b2v2[r] + gt[3] * b2v3[r]
                        + x[addr];
                out[addr] = v;
            }
        }
    }

    __syncthreads();
    if (tid < 4) {
        atomicAdd(&stat[tid], simp[tid]);
        atomicAdd(&stat[4 + tid], sload[tid]);
    }
}

// ---------------- K_loss ----------------
__global__ void k_loss(const float* __restrict__ stat, float* __restrict__ out) {
    if (threadIdx.x == 0 && blockIdx.x == 0) {
        double mi = 0.0, ml = 0.0;
        for (int e = 0; e < 4; ++e) { mi += stat[e]; ml += stat[4 + e]; }
        mi *= 0.25; ml *= 0.25;
        double vi = 0.0, vl = 0.0;
        for (int e = 0; e < 4; ++e) {
            double di = stat[e] - mi; vi += di * di;
            double dl = stat[4 + e] - ml; vl += dl * dl;
        }
        vi *= 0.25; vl *= 0.25;
        out[OUT_Y_ELEMS] = (float)(0.01 * (vi / (mi * mi + 1e-10) + vl / (ml * ml + 1e-10)));
    }
}

extern "C" void kernel_launch(void* const* d_in, const int* in_sizes, int n_in,
                              void* d_out, int out_size, void* d_ws, size_t ws_size,
                              hipStream_t stream) {
    const float* x      = (const float*)d_in[0];
    const float* prompt = (const float*)d_in[1];
    const float* wlin   = (const float*)d_in[2];
    const float* blin   = (const float*)d_in[3];
    const float* wconv  = (const float*)d_in[4];
    const float* wgate  = (const float*)d_in[5];
    const float* w1     = (const float*)d_in[6];
    const float* b1     = (const float*)d_in[7];
    const float* w2     = (const float*)d_in[8];
    const float* b2     = (const float*)d_in[9];
    float* out = (float*)d_out;

    char* ws = (char*)d_ws;
    float* emb  = (float*)(ws + 0);              // 256 f32
    float* stat = (float*)(ws + 1024);           // 8 f32
    float* b1c  = (float*)(ws + 2048);           // 1408 f32 -> ends 7680
    short* WbBf = (short*)(ws + 8192);           // 32768 bf16 -> ends 73728
    unsigned char* Wall = (unsigned char*)(ws + 73728);  // 360448 fp8 -> ends 434176

    hipLaunchKernelGGL(k_prep, dim3(610),  dim3(256), 0, stream, x, w1, w2, b1, emb, Wall, b1c);
    hipLaunchKernelGGL(k_wb,   dim3(32),   dim3(256), 0, stream, emb, prompt, wlin, blin, wconv, WbBf, stat);
    hipLaunchKernelGGL(k_main, dim3(768),  dim3(192), 0, stream, x, wgate, b2, WbBf, Wall, b1c, stat, out);
    hipLaunchKernelGGL(k_loss, dim3(1),    dim3(1),   0, stream, stat, out);
}

// Round 9
// 93.762 us; speedup vs baseline: 1.8272x; 1.8272x over previous
//
#include <hip/hip_runtime.h>
#include <hip/hip_bf16.h>
#include <hip/hip_fp8.h>

typedef __attribute__((ext_vector_type(8))) short bf16x8;
typedef __attribute__((ext_vector_type(4))) float f32x4;
typedef long long i64;
typedef __attribute__((ext_vector_type(2))) long long i64x2;

#define HW 36864
#define HID 340
#define HPAD 352
#define ECP 1408
#define NCHUNK 44
#define TILE 96
#define TILES_PER_B 384
#define OUT_Y_ELEMS 9437184
#define WALL_BYTES (NCHUNK * 8192)

__device__ __forceinline__ short f2bf(float f) {
    __hip_bfloat16 h = __float2bfloat16(f);
    union { __hip_bfloat16 h; short s; } u; u.h = h; return u.s;
}
__device__ __forceinline__ float bf2f(short s) {
    union { unsigned u; float f; } v; v.u = ((unsigned)(unsigned short)s) << 16; return v.f;
}
__device__ __forceinline__ f32x4 mfma_fp8(i64 a, i64 b, f32x4 c) {
    return __builtin_amdgcn_mfma_f32_16x16x32_fp8_fp8(a, b, c, 0, 0, 0);
}
__device__ __forceinline__ void async_cp16(const void* gsrc, void* ldst) {
    __builtin_amdgcn_global_load_lds(
        (const __attribute__((address_space(1))) unsigned int*)gsrc,
        (__attribute__((address_space(3))) unsigned int*)ldst, 16, 0, 0);
}

// ---------------- K_prep: emb + fp8 weight prepack (DMA-ring layout) + b1c ----------------
// Per chunk (8192B): addr = r*1024 + lane*16 + j   (lane = g16*16+l16, j=0..15)
//  r<4 (fc1): m=r>>1, p=r&1, kk=2p+(j>>3), jj=j&7:
//    val = w1[e][c][h]*32 with j_h=ch*32+m*16+l16, c=16*(2kk+(jj>>2))+4*g16+(jj&3)
//  r>=4 (fc2): q=r-4, oc=2q+(j>>3), jj=j&7:
//    val = w2[e][h][o]*32 with o=oc*16+l16, jg=ch*32+16*(jj>>2)+4*g16+(jj&3)
__global__ __launch_bounds__(256) void k_prep(const float* __restrict__ x,
                                              const float* __restrict__ w1, const float* __restrict__ w2,
                                              const float* __restrict__ b1,
                                              float* __restrict__ emb, unsigned char* __restrict__ Wall,
                                              float* __restrict__ b1c) {
    int blk = blockIdx.x;
    int tid = threadIdx.x;
    if (blk < 256) {
        const float* p = x + (size_t)blk * HW;
        float s = 0.f;
        for (int i = tid * 4; i < HW; i += 1024) {
            float4 v = *(const float4*)(p + i);
            s += v.x + v.y + v.z + v.w;
        }
        for (int off = 32; off; off >>= 1) s += __shfl_down(s, off);
        __shared__ float wsum[4];
        int lane = tid & 63, wid = tid >> 6;
        if (lane == 0) wsum[wid] = s;
        __syncthreads();
        if (tid == 0) emb[blk] = (wsum[0] + wsum[1] + wsum[2] + wsum[3]) * (1.f / (float)HW);
        return;
    }
    if (blk < 608) {
        int idx4 = (blk - 256) * 1024 + tid * 4;   // 4-aligned
        int ch = idx4 >> 13, r8 = idx4 & 8191;
        int rr = r8 >> 10;
        int lane = (r8 >> 4) & 63;
        int j0 = r8 & 15;                 // 0,4,8,12
        int g16 = lane >> 4, l16 = lane & 15;
        int jj0 = j0 & 7;                 // 0 or 4
        float v0 = 0.f, v1 = 0.f, v2 = 0.f, v3 = 0.f;
        if (rr < 4) {
            int m = rr >> 1, p = rr & 1;
            int kk = 2 * p + (j0 >> 3);
            int j_h = ch * 32 + m * 16 + l16;
            int c0 = 16 * (2 * kk + (jj0 >> 2)) + 4 * g16;
            int e = j_h / HPAD, h = j_h - e * HPAD;
            if (h < HID) {
                const float* p1 = w1 + ((size_t)(e * 128 + c0)) * HID + h;
                v0 = p1[0] * 32.f; v1 = p1[HID] * 32.f; v2 = p1[2 * HID] * 32.f; v3 = p1[3 * HID] * 32.f;
            }
        } else {
            int q = rr - 4;
            int oc = 2 * q + (j0 >> 3);
            int o = oc * 16 + l16;
            int jg0 = ch * 32 + 16 * (jj0 >> 2) + 4 * g16;
            int e = jg0 / HPAD, h = jg0 - e * HPAD;
            if (h < HID) {
                const float* p2 = w2 + ((size_t)(e * HID + h)) * 128 + o;
                v0 = p2[0] * 32.f; v1 = p2[128] * 32.f; v2 = p2[256] * 32.f; v3 = p2[384] * 32.f;
            }
        }
        unsigned w = __builtin_amdgcn_cvt_pk_fp8_f32(v0, v1, 0, false);
        w = __builtin_amdgcn_cvt_pk_fp8_f32(v2, v3, w, true);
        *(unsigned*)(Wall + idx4) = w;
        return;
    }
    {
        int j0 = (blk - 608) * 1024 + tid * 4;
        if (j0 < ECP) {
            int e = j0 / HPAD, h = j0 - e * HPAD;
            float4 o;
            if (h < HID) {
                const float* p = b1 + e * HID + h;
                o.x = p[0]; o.y = p[1]; o.z = p[2]; o.w = p[3];
            } else {
                o.x = o.y = o.z = o.w = 0.f;
            }
            *(float4*)(b1c + j0) = o;
        }
    }
}

// ---------------- K_wb: prompt path + folded conv weights ----------------
__global__ __launch_bounds__(256) void k_wb(const float* __restrict__ emb, const float* __restrict__ prompt,
                                            const float* __restrict__ wlin, const float* __restrict__ blin,
                                            const float* __restrict__ wconv,
                                            short* __restrict__ WbBf, float* __restrict__ stat) {
    __shared__ float lp[2][5];
    __shared__ float pw[2][5];
    __shared__ float sv[2][128];
    int tid = threadIdx.x;
    if (tid < 10) {
        int b = tid / 5, p = tid % 5;
        float s = blin[p];
        for (int c = 0; c < 128; ++c) s += emb[b * 128 + c] * wlin[p * 128 + c];
        lp[b][p] = s;
    }
    __syncthreads();
    if (tid < 2) {
        float m = lp[tid][0];
        for (int p = 1; p < 5; ++p) m = fmaxf(m, lp[tid][p]);
        float e[5], sum = 0.f;
        for (int p = 0; p < 5; ++p) { e[p] = __expf(lp[tid][p] - m); sum += e[p]; }
        for (int p = 0; p < 5; ++p) pw[tid][p] = e[p] / sum;
    }
    __syncthreads();
    {
        int b = tid >> 7, c = tid & 127;
        float s = 0.f;
        for (int p = 0; p < 5; ++p) s += pw[b][p] * prompt[p * 128 + c];
        sv[b][c] = s;
    }
    __syncthreads();
    int i0 = blockIdx.x * 1024 + tid * 4;
    int b = i0 >> 14, o = (i0 >> 7) & 127, c = i0 & 127;
    float4 wv = *(const float4*)(wconv + o * 128 + c);
    short r0 = f2bf(wv.x * sv[b][c]);
    short r1 = f2bf(wv.y * sv[b][c + 1]);
    short r2 = f2bf(wv.z * sv[b][c + 2]);
    short r3 = f2bf(wv.w * sv[b][c + 3]);
    WbBf[i0] = r0; WbBf[i0 + 1] = r1; WbBf[i0 + 2] = r2; WbBf[i0 + 3] = r3;
    if (blockIdx.x == 0 && tid < 8) stat[tid] = 0.f;
}

// ---------------- K_main: 768 blocks x 192 threads; LDS DMA ring, counted vmcnt ----------------
__global__ __launch_bounds__(192, 3) void k_main(
    const float* __restrict__ x, const float* __restrict__ wgate, const float* __restrict__ b2,
    const short* __restrict__ WbBf, const unsigned char* __restrict__ Wall,
    const float* __restrict__ b1c, float* __restrict__ stat, float* __restrict__ out) {

    __shared__ __align__(16) short Xs[TILE][136];                 // 26112 B
    __shared__ __align__(16) unsigned char ring[3][8192];         // 24576 B
    __shared__ __align__(16) short b1sh[ECP];                     // 2816 B
    __shared__ float simp[4], sload[4];                           // 32 B -> total 53536 B (3 blocks/CU)
    float* gates = (float*)&ring[2][0];   // [96][4] overlay; dead before slot2's first DMA write

    int tid = threadIdx.x;
    int tb = blockIdx.x;
    int b = tb / TILES_PER_B;
    int hw0 = (tb % TILES_PER_B) * TILE;
    const float* xb = x + (size_t)b * 128 * HW + hw0;

    int lane = tid & 63, wid = tid >> 6;
    int g16 = lane >> 4, l16 = lane & 15;
    int wrow = wid * 32;

    // ---- issue DMA for chunks 0,1 (wave0: fc1 half, wave1: fc2 half) ----
    if (wid < 2) {
        const unsigned char* s0 = Wall + wid * 4096;
        #pragma unroll
        for (int r = 0; r < 4; ++r)
            async_cp16(s0 + r * 1024 + lane * 16, &ring[0][wid * 4096 + r * 1024 + lane * 16]);
        const unsigned char* s1 = Wall + 8192 + wid * 4096;
        #pragma unroll
        for (int r = 0; r < 4; ++r)
            async_cp16(s1 + r * 1024 + lane * 16, &ring[1][wid * 4096 + r * 1024 + lane * 16]);
    }

    if (tid < 4) { simp[tid] = 0.f; sload[tid] = 0.f; }
    for (int i = tid; i < ECP; i += 192) b1sh[i] = f2bf(b1c[i]);

    // ---- stage X tile (bf16) ----
    #pragma unroll
    for (int it = 0; it < 16; ++it) {
        int i = tid + it * 192;
        int c = i / 24;
        int k = i - c * 24;
        float4 v = *(const float4*)(xb + (size_t)c * HW + k * 4);
        int t = k * 4;
        Xs[t][c] = f2bf(v.x); Xs[t + 1][c] = f2bf(v.y);
        Xs[t + 2][c] = f2bf(v.z); Xs[t + 3][c] = f2bf(v.w);
    }
    __syncthreads();   // implicit full drain: ch0/ch1 DMA landed; Xs complete

    // ---- X fragments ----
    bf16x8 xf[2][4];
    #pragma unroll
    for (int nt = 0; nt < 2; ++nt)
        #pragma unroll
        for (int kk = 0; kk < 4; ++kk)
            xf[nt][kk] = *(const bf16x8*)&Xs[wrow + nt * 16 + l16][kk * 32 + g16 * 8];

    // ---- gating via MFMA (wgate read from global; rows>=4 zero) ----
    {
        bf16x8 wgA[4];
        #pragma unroll
        for (int kk = 0; kk < 4; ++kk) {
            bf16x8 a = (bf16x8){0, 0, 0, 0, 0, 0, 0, 0};
            if (l16 < 4) {
                #pragma unroll
                for (int jj = 0; jj < 8; ++jj)
                    a[jj] = f2bf(wgate[(kk * 32 + g16 * 8 + jj) * 4 + l16]);
            }
            wgA[kk] = a;
        }
        f32x4 lg0 = (f32x4){0.f, 0.f, 0.f, 0.f};
        f32x4 lg1 = (f32x4){0.f, 0.f, 0.f, 0.f};
        #pragma unroll
        for (int kk = 0; kk < 4; ++kk) {
            lg0 = __builtin_amdgcn_mfma_f32_16x16x32_bf16(wgA[kk], xf[0][kk], lg0, 0, 0, 0);
            lg1 = __builtin_amdgcn_mfma_f32_16x16x32_bf16(wgA[kk], xf[1][kk], lg1, 0, 0, 0);
        }
        if (g16 == 0) {
            #pragma unroll
            for (int nt = 0; nt < 2; ++nt) {
                f32x4 lg = nt ? lg1 : lg0;
                float l0 = lg[0], l1 = lg[1], l2 = lg[2], l3 = lg[3];
                int i1 = 0; float m1 = l0;
                if (l1 > m1) { m1 = l1; i1 = 1; }
                if (l2 > m1) { m1 = l2; i1 = 2; }
                if (l3 > m1) { m1 = l3; i1 = 3; }
                float m2 = -3.4e38f; int i2 = 0;
                if (i1 != 0) { m2 = l0; i2 = 0; }
                if (i1 != 1 && l1 > m2) { m2 = l1; i2 = 1; }
                if (i1 != 2 && l2 > m2) { m2 = l2; i2 = 2; }
                if (i1 != 3 && l3 > m2) { m2 = l3; i2 = 3; }
                float g2v = 1.f / (1.f + __expf(m1 - m2));
                float g1v = 1.f - g2v;
                int t = wrow + nt * 16 + l16;
                gates[t * 4 + 0] = 0.f; gates[t * 4 + 1] = 0.f;
                gates[t * 4 + 2] = 0.f; gates[t * 4 + 3] = 0.f;
                gates[t * 4 + i1] = g1v; gates[t * 4 + i2] = g2v;
                atomicAdd(&simp[i1], g1v); atomicAdd(&simp[i2], g2v);
                atomicAdd(&sload[i1], 1.f); atomicAdd(&sload[i2], 1.f);
            }
        }
    }

    // ---- conv (bf16): aty[nt][oc] = ty[t][o] ----
    f32x4 aty[2][8];
    #pragma unroll
    for (int nt = 0; nt < 2; ++nt)
        #pragma unroll
        for (int oc = 0; oc < 8; ++oc) aty[nt][oc] = (f32x4){0.f, 0.f, 0.f, 0.f};
    {
        const short* wbB = WbBf + b * 16384 + l16 * 128 + g16 * 8;
        #pragma unroll
        for (int oc = 0; oc < 8; ++oc) {
            #pragma unroll
            for (int kk = 0; kk < 4; ++kk) {
                bf16x8 wv = *(const bf16x8*)(wbB + oc * 16 * 128 + kk * 32);
                aty[0][oc] = __builtin_amdgcn_mfma_f32_16x16x32_bf16(wv, xf[0][kk], aty[0][oc], 0, 0, 0);
                aty[1][oc] = __builtin_amdgcn_mfma_f32_16x16x32_bf16(wv, xf[1][kk], aty[1][oc], 0, 0, 0);
            }
        }
    }
    // repack to fp8 B-fragments (x64 prescale)
    i64 tyb8[2][4];
    #pragma unroll
    for (int nt = 0; nt < 2; ++nt)
        #pragma unroll
        for (int kk = 0; kk < 4; ++kk) {
            union { i64 l; unsigned u[2]; } uu;
            float v0 = aty[nt][2 * kk][0] * 64.f,     v1 = aty[nt][2 * kk][1] * 64.f;
            float v2 = aty[nt][2 * kk][2] * 64.f,     v3 = aty[nt][2 * kk][3] * 64.f;
            float v4 = aty[nt][2 * kk + 1][0] * 64.f, v5 = aty[nt][2 * kk + 1][1] * 64.f;
            float v6 = aty[nt][2 * kk + 1][2] * 64.f, v7 = aty[nt][2 * kk + 1][3] * 64.f;
            unsigned lo = __builtin_amdgcn_cvt_pk_fp8_f32(v0, v1, 0, false);
            lo = __builtin_amdgcn_cvt_pk_fp8_f32(v2, v3, lo, true);
            unsigned hi = __builtin_amdgcn_cvt_pk_fp8_f32(v4, v5, 0, false);
            hi = __builtin_amdgcn_cvt_pk_fp8_f32(v6, v7, hi, true);
            uu.u[0] = lo; uu.u[1] = hi;
            tyb8[nt][kk] = uu.l;
        }

    // per-lane gates (written by this wave's g16==0 lanes; same-wave LDS)
    f32x4 gt0 = *(const f32x4*)&gates[(wrow + l16) * 4];
    f32x4 gt1 = *(const f32x4*)&gates[(wrow + 16 + l16) * 4];

    f32x4 accy[2][8];
    #pragma unroll
    for (int nt = 0; nt < 2; ++nt)
        #pragma unroll
        for (int oc = 0; oc < 8; ++oc) accy[nt][oc] = (f32x4){0.f, 0.f, 0.f, 0.f};

    // ---- main loop: ring slots, counted vmcnt, one barrier per chunk ----
    int slot = 0;
    #pragma unroll 1
    for (int ch = 0; ch < NCHUNK; ++ch) {
        if (wid < 2) asm volatile("s_waitcnt vmcnt(4)" ::: "memory");
        __builtin_amdgcn_sched_barrier(0);
        __builtin_amdgcn_s_barrier();
        __builtin_amdgcn_sched_barrier(0);

        // issue chunk ch+2 into slot (slot+2)%3 (clamped dummy at tail keeps count uniform)
        if (wid < 2) {
            int chn = (ch + 2 <= NCHUNK - 1) ? ch + 2 : NCHUNK - 1;
            int wslot = slot + 2; if (wslot >= 3) wslot -= 3;
            const unsigned char* src = Wall + (size_t)chn * 8192 + wid * 4096;
            unsigned char* dst = &ring[wslot][wid * 4096];
            #pragma unroll
            for (int r = 0; r < 4; ++r)
                async_cp16(src + r * 1024 + lane * 16, dst + r * 1024 + lane * 16);
        }

        // fragment reads from LDS (conflict-free: lane*16 stride)
        const unsigned char* wst = &ring[slot][0];
        i64x2 f1q[2][2], f2q[4];
        f1q[0][0] = *(const i64x2*)(wst + 0 * 1024 + lane * 16);
        f1q[0][1] = *(const i64x2*)(wst + 1 * 1024 + lane * 16);
        f1q[1][0] = *(const i64x2*)(wst + 2 * 1024 + lane * 16);
        f1q[1][1] = *(const i64x2*)(wst + 3 * 1024 + lane * 16);
        f2q[0] = *(const i64x2*)(wst + 4 * 1024 + lane * 16);
        f2q[1] = *(const i64x2*)(wst + 5 * 1024 + lane * 16);
        f2q[2] = *(const i64x2*)(wst + 6 * 1024 + lane * 16);
        f2q[3] = *(const i64x2*)(wst + 7 * 1024 + lane * 16);

        int e4 = (ch >= 33) ? 3 : (ch >= 22) ? 2 : (ch >= 11) ? 1 : 0;
        float ge0 = (e4 == 0) ? gt0[0] : (e4 == 1) ? gt0[1] : (e4 == 2) ? gt0[2] : gt0[3];
        float ge1 = (e4 == 0) ? gt1[0] : (e4 == 1) ? gt1[1] : (e4 == 2) ? gt1[2] : gt1[3];

        // fc1 (fp8)
        f32x4 hacc[2][2];
        hacc[0][0] = (f32x4){0.f,0.f,0.f,0.f}; hacc[0][1] = (f32x4){0.f,0.f,0.f,0.f};
        hacc[1][0] = (f32x4){0.f,0.f,0.f,0.f}; hacc[1][1] = (f32x4){0.f,0.f,0.f,0.f};
        #pragma unroll
        for (int kk = 0; kk < 4; ++kk) {
            i64 a0 = f1q[0][kk >> 1][kk & 1];
            i64 a1 = f1q[1][kk >> 1][kk & 1];
            hacc[0][0] = mfma_fp8(a0, tyb8[0][kk], hacc[0][0]);
            hacc[0][1] = mfma_fp8(a0, tyb8[1][kk], hacc[0][1]);
            hacc[1][0] = mfma_fp8(a1, tyb8[0][kk], hacc[1][0]);
            hacc[1][1] = mfma_fp8(a1, tyb8[1][kk], hacc[1][1]);
        }

        // bias (bf16 LDS) + Taylor-gelu + gate -> fp8 fc2 B-frags
        float hv0[8], hv1[8];
        #pragma unroll
        for (int jc = 0; jc < 2; ++jc)
            #pragma unroll
            for (int rr = 0; rr < 4; ++rr) {
                float bv = bf2f(b1sh[ch * 32 + jc * 16 + 4 * g16 + rr]);
                float u0 = hacc[jc][0][rr] * 4.8828125e-4f + bv;
                float u1 = hacc[jc][1][rr] * 4.8828125e-4f + bv;
                hv0[jc * 4 + rr] = u0 * (1024.f + 816.9738f * u0) * ge0;
                hv1[jc * 4 + rr] = u1 * (1024.f + 816.9738f * u1) * ge1;
            }
        union { i64 l; unsigned u[2]; } f0, f1;
        {
            unsigned lo = __builtin_amdgcn_cvt_pk_fp8_f32(hv0[0], hv0[1], 0, false);
            lo = __builtin_amdgcn_cvt_pk_fp8_f32(hv0[2], hv0[3], lo, true);
            unsigned hi = __builtin_amdgcn_cvt_pk_fp8_f32(hv0[4], hv0[5], 0, false);
            hi = __builtin_amdgcn_cvt_pk_fp8_f32(hv0[6], hv0[7], hi, true);
            f0.u[0] = lo; f0.u[1] = hi;
            lo = __builtin_amdgcn_cvt_pk_fp8_f32(hv1[0], hv1[1], 0, false);
            lo = __builtin_amdgcn_cvt_pk_fp8_f32(hv1[2], hv1[3], lo, true);
            hi = __builtin_amdgcn_cvt_pk_fp8_f32(hv1[4], hv1[5], 0, false);
            hi = __builtin_amdgcn_cvt_pk_fp8_f32(hv1[6], hv1[7], hi, true);
            f1.u[0] = lo; f1.u[1] = hi;
        }

        // fc2 (fp8)
        #pragma unroll
        for (int oc = 0; oc < 8; ++oc) {
            i64 wv = f2q[oc >> 1][oc & 1];
            accy[0][oc] = mfma_fp8(wv, f0.l, accy[0][oc]);
            accy[1][oc] = mfma_fp8(wv, f1.l, accy[1][oc]);
        }

        slot = (slot == 2) ? 0 : slot + 1;
    }

    // ---- epilogue: descale + gates.b2 (global) + residual, store ----
    #pragma unroll
    for (int oc = 0; oc < 8; ++oc) {
        f32x4 b2v0 = *(const f32x4*)&b2[0 * 128 + oc * 16 + 4 * g16];
        f32x4 b2v1 = *(const f32x4*)&b2[1 * 128 + oc * 16 + 4 * g16];
        f32x4 b2v2 = *(const f32x4*)&b2[2 * 128 + oc * 16 + 4 * g16];
        f32x4 b2v3 = *(const f32x4*)&b2[3 * 128 + oc * 16 + 4 * g16];
        #pragma unroll
        for (int nt = 0; nt < 2; ++nt) {
            f32x4 gt = nt ? gt1 : gt0;
            #pragma unroll
            for (int r = 0; r < 4; ++r) {
                int o = oc * 16 + 4 * g16 + r;
                size_t addr = (size_t)(b * 128 + o) * HW + hw0 + wrow + nt * 16 + l16;
                float v = accy[nt][oc][r] * 1.52587890625e-5f
                        + gt[0] * b2v0[r] + gt[1] * b2v1[r] + gt[2] * b2v2[r] + gt[3] * b2v3[r]
                        + x[addr];
                out[addr] = v;
            }
        }
    }

    __syncthreads();
    if (tid < 4) {
        atomicAdd(&stat[tid], simp[tid]);
        atomicAdd(&stat[4 + tid], sload[tid]);
    }
}

// ---------------- K_loss ----------------
__global__ void k_loss(const float* __restrict__ stat, float* __restrict__ out) {
    if (threadIdx.x == 0 && blockIdx.x == 0) {
        double mi = 0.0, ml = 0.0;
        for (int e = 0; e < 4; ++e) { mi += stat[e]; ml += stat[4 + e]; }
        mi *= 0.25; ml *= 0.25;
        double vi = 0.0, vl = 0.0;
        for (int e = 0; e < 4; ++e) {
            double di = stat[e] - mi; vi += di * di;
            double dl = stat[4 + e] - ml; vl += dl * dl;
        }
        vi *= 0.25; vl *= 0.25;
        out[OUT_Y_ELEMS] = (float)(0.01 * (vi / (mi * mi + 1e-10) + vl / (ml * ml + 1e-10)));
    }
}

extern "C" void kernel_launch(void* const* d_in, const int* in_sizes, int n_in,
                              void* d_out, int out_size, void* d_ws, size_t ws_size,
                              hipStream_t stream) {
    const float* x      = (const float*)d_in[0];
    const float* prompt = (const float*)d_in[1];
    const float* wlin   = (const float*)d_in[2];
    const float* blin   = (const float*)d_in[3];
    const float* wconv  = (const float*)d_in[4];
    const float* wgate  = (const float*)d_in[5];
    const float* w1     = (const float*)d_in[6];
    const float* b1     = (const float*)d_in[7];
    const float* w2     = (const float*)d_in[8];
    const float* b2     = (const float*)d_in[9];
    float* out = (float*)d_out;

    char* ws = (char*)d_ws;
    float* emb  = (float*)(ws + 0);              // 256 f32
    float* stat = (float*)(ws + 1024);           // 8 f32
    float* b1c  = (float*)(ws + 2048);           // 1408 f32 -> ends 7680
    short* WbBf = (short*)(ws + 8192);           // 32768 bf16 -> ends 73728
    unsigned char* Wall = (unsigned char*)(ws + 73728);  // 360448 fp8 -> ends 434176

    hipLaunchKernelGGL(k_prep, dim3(610),  dim3(256), 0, stream, x, w1, w2, b1, emb, Wall, b1c);
    hipLaunchKernelGGL(k_wb,   dim3(32),   dim3(256), 0, stream, emb, prompt, wlin, blin, wconv, WbBf, stat);
    hipLaunchKernelGGL(k_main, dim3(768),  dim3(192), 0, stream, x, wgate, b2, WbBf, Wall, b1c, stat, out);
    hipLaunchKernelGGL(k_loss, dim3(1),    dim3(1),   0, stream, stat, out);
}